// Round 7
// baseline (50.015 us; speedup 1.0000x reference)
//
#include <hip/hip_runtime.h>

// PewLSTM HS=1, 2-lane systolic (even lane = layer1 @ t, odd = layer2 @ t-1,
// h handed off via DPP quad_perm). R7: ALL transcendentals replaced by
// short-latency software sequences -- the wall-clock is T x per-step chain
// latency, and v_exp/v_rcp dependent latency measured ~100 cy each (4 in
// chain = 460 cy/step). Soft exp2/rcp cut the chain to ~170 cy/step.

constexpr int BB  = 32768;
constexpr int TT  = 168;
constexpr int CHS = 8;            // timesteps per chunk
constexpr int CHV = 10;           // float4 per chunk
constexpr int NCH = 21;           // chunks

#define LOG2E   1.44269504088896341f
#define NEG2L   (-2.88539008177792681f)
#define A0CLAMP 37.0f             // preact clamp: keeps den <= ~2^123

__device__ __forceinline__ float lane_swap(float x) {   // quad_perm(1,0,3,2)
    return __int_as_float(
        __builtin_amdgcn_mov_dpp(__float_as_int(x), 0xB1, 0xF, 0xF, true));
}

// software exp2: chain ~28 cy vs ~100 for v_exp_f32.
// deg-6 poly on f in [0,1) (Estrin), exponent via integer scale construct.
// n clamped to [-126, 60]: gate args <= 43 are exact; tanh args beyond 60
// saturate identically after the (1-e)/(1+e) form.
__device__ __forceinline__ float exp2_soft(float x) {
    float n  = floorf(x);
    float f  = x - n;
    float nc = fminf(fmaxf(n, -126.0f), 60.0f);
    int   ni = (int)nc;
    float scale = __int_as_float((ni + 127) << 23);
    float f2  = f * f;
    float p01 = fmaf(f, 0.6931471805599453f,    1.0f);
    float p23 = fmaf(f, 0.05550410866482158f,   0.2402265069591007f);
    float p45 = fmaf(f, 0.0013333558146428443f, 0.009618129107628477f);
    float inn = fmaf(f2, 0.00015403530393381606f, p45);
    float f4  = f2 * f2;
    float t1  = fmaf(f2, p23, p01);
    float t2  = fmaf(f4, inn, t1);
    return t2 * scale;
}

// software rcp for x in (0, 2^123]: bit-magic seed + 3 NR (fma form).
// chain ~28 cy vs ~100 for v_rcp_f32; rel err ~1e-7.
__device__ __forceinline__ float rcp_soft(float x) {
    float y = __int_as_float(0x7EF311C3 - __float_as_int(x));
    float e;
    e = fmaf(-x, y, 1.0f); y = fmaf(y, e, y);
    e = fmaf(-x, y, 1.0f); y = fmaf(y, e, y);
    e = fmaf(-x, y, 1.0f); y = fmaf(y, e, y);
    return y;
}

__global__ __launch_bounds__(64, 1) void pewlstm_kernel(
    const float* __restrict__ in,
    const float* __restrict__ W1ih, const float* __restrict__ W1hh,
    const float* __restrict__ W1wh, const float* __restrict__ b1,
    const float* __restrict__ W2ih, const float* __restrict__ W2hh,
    const float* __restrict__ W2wh, const float* __restrict__ b2,
    const float* __restrict__ fcw, const float* __restrict__ fcb,
    float* __restrict__ out)
{
    const int tid = blockIdx.x * 64 + threadIdx.x;
    const int b   = tid >> 1;            // sequence index
    const int l2  = tid & 1;             // 1 = layer-2 lane
    const float l2f = l2 ? 1.0f : 0.0f;

    const float* Wih = l2 ? W2ih : W1ih;
    const float* Whh = l2 ? W2hh : W1hh;
    const float* Wwh = l2 ? W2wh : W1wh;
    const float* Bv  = l2 ? b2   : b1;

    // gate order [i,f,g,o]; pre-scale by -log2e (g: -2log2e) so exp2 is direct
    float wih[4], whh[4], bbv[4], wwh[16];
#pragma unroll
    for (int g = 0; g < 4; ++g) {
        const float s = (g == 2) ? NEG2L : -LOG2E;
        wih[g] = Wih[g] * s; whh[g] = Whh[g] * s; bbv[g] = Bv[g] * s;
    }
#pragma unroll
    for (int k = 0; k < 16; ++k) {
        const float s = ((k & 3) == 2) ? NEG2L : -LOG2E;
        wwh[k] = Wwh[k] * s;
    }
    const float fw = fcw[0], fbv = fcb[0];

    const float4* __restrict__ row =
        reinterpret_cast<const float4*>(in + (size_t)b * (TT * 5));
    float4* orow = reinterpret_cast<float4*>(out + (size_t)b * TT);

    float4 bufA[CHV], bufB[CHV];
    float h = 0.f, cc = 0.f, h1x = 0.f;
    float xc0 = 0.f, xc1 = 0.f, xc2 = 0.f, xc3 = 0.f;  // prev chunk last weather
    float ob[CHS];

    auto issue = [&](float4 (&buf)[CHV], int c2) {
#pragma unroll
        for (int i = 0; i < CHV; ++i) buf[i] = row[c2 * CHV + i];
    };

    auto process = [&](float4 (&buf)[CHV], int c, bool is0) {
        float cur[CHS * 5];
#pragma unroll
        for (int i = 0; i < CHV; ++i) {
            cur[4*i+0] = buf[i].x; cur[4*i+1] = buf[i].y;
            cur[4*i+2] = buf[i].z; cur[4*i+3] = buf[i].w;
        }
#pragma unroll
        for (int s = 0; s < CHS; ++s) {
            // L1 lanes use weather(t)/x(t); L2 lanes weather(t-1)
            const float w0 = l2 ? (s == 0 ? xc0 : cur[(s-1)*5+0]) : cur[s*5+0];
            const float w1 = l2 ? (s == 0 ? xc1 : cur[(s-1)*5+1]) : cur[s*5+1];
            const float w2 = l2 ? (s == 0 ? xc2 : cur[(s-1)*5+2]) : cur[s*5+2];
            const float w3 = l2 ? (s == 0 ? xc3 : cur[(s-1)*5+3]) : cur[s*5+3];
            const float xi = l2 ? 0.0f : cur[s*5+4];

            // x-dependent pre-activations (off-chain; clamped for overflow)
            float a0[4];
#pragma unroll
            for (int g = 0; g < 4; ++g) {
                float p = bbv[g];
                p = fmaf(w0, wwh[0  + g], p);
                p = fmaf(w1, wwh[4  + g], p);
                p = fmaf(w2, wwh[8  + g], p);
                p = fmaf(w3, wwh[12 + g], p);
                p = fmaf(xi, wih[g], p);
                a0[g] = fminf(p, A0CLAMP);
            }

            // recurrent terms + soft activations
            const float inv = h1x * l2f;               // L2: h1(t-1)
            const float aI = fmaf(h, whh[0], fmaf(inv, wih[0], a0[0]));
            const float aF = fmaf(h, whh[1], fmaf(inv, wih[1], a0[1]));
            const float aG = fmaf(h, whh[2], fmaf(inv, wih[2], a0[2]));
            const float aO = fmaf(h, whh[3], fmaf(inv, wih[3], a0[3]));
            const float eI = exp2_soft(aI);            // e^-ai
            const float eF = exp2_soft(aF);            // e^-af
            const float eG = exp2_soft(aG);            // e^-2ag
            const float eO = exp2_soft(aO);            // e^-ao
            const float dI = 1.f + eI, dF = 1.f + eF;
            const float dG = 1.f + eG, dO = 1.f + eO;
            const float nG = 1.f - eG;
            // c' = (c*dI*dG + nG*dF) / (dF*dI*dG)
            const float p   = dI * dG;
            const float num = fmaf(cc, p, nG * dF);
            cc = num * rcp_soft(dF * p);
            // h = (1-eC) / (dO*(1+eC)), eC = 2^(c'*-2log2e)
            const float eC = exp2_soft(cc * NEG2L);
            h = (1.f - eC) * rcp_soft(dO * (1.f + eC));

            if (s == 0 && is0) { if (l2) { h = 0.f; cc = 0.f; } }  // phantom

            ob[(s + 7) & 7] = fmaf(h, fw, fbv);        // true h2 on l2 lane

            if (s == 0 && c >= 1 && l2) {              // flush prev chunk
                orow[(c-1)*2+0] = make_float4(ob[0], ob[1], ob[2], ob[3]);
                orow[(c-1)*2+1] = make_float4(ob[4], ob[5], ob[6], ob[7]);
            }

            h1x = lane_swap(h);    // partner's h (L2 lanes get h1(t))
        }
        xc0 = cur[35]; xc1 = cur[36]; xc2 = cur[37]; xc3 = cur[38];
    };

    // pipeline: A/B prefetch double-buffer
    issue(bufA, 0);
    for (int cp = 0; cp < 10; ++cp) {
        issue(bufB, 2 * cp + 1);
        process(bufA, 2 * cp, cp == 0);
        issue(bufA, 2 * cp + 2);
        process(bufB, 2 * cp + 1, false);
    }
    process(bufA, 20, false);

    // epilogue step t=168: L2 lane computes h2(167)
    {
        float a[4];
#pragma unroll
        for (int g = 0; g < 4; ++g) {
            float pp = bbv[g];
            pp = fmaf(xc0, wwh[0  + g], pp);
            pp = fmaf(xc1, wwh[4  + g], pp);
            pp = fmaf(xc2, wwh[8  + g], pp);
            pp = fmaf(xc3, wwh[12 + g], pp);
            pp = fminf(pp, A0CLAMP);
            pp = fmaf(h1x, wih[g], pp);
            a[g] = fmaf(h, whh[g], pp);
        }
        const float eI = exp2_soft(a[0]);
        const float eF = exp2_soft(a[1]);
        const float eG = exp2_soft(a[2]);
        const float eO = exp2_soft(a[3]);
        const float dI = 1.f + eI, dF = 1.f + eF;
        const float dG = 1.f + eG, dO = 1.f + eO;
        const float nG = 1.f - eG;
        const float p   = dI * dG;
        const float num = fmaf(cc, p, nG * dF);
        cc = num * rcp_soft(dF * p);
        const float eC = exp2_soft(cc * NEG2L);
        h = (1.f - eC) * rcp_soft(dO * (1.f + eC));
        ob[7] = fmaf(h, fw, fbv);
        if (l2) {
            orow[(NCH-1)*2+0] = make_float4(ob[0], ob[1], ob[2], ob[3]);
            orow[(NCH-1)*2+1] = make_float4(ob[4], ob[5], ob[6], ob[7]);
        }
    }
}

extern "C" void kernel_launch(void* const* d_in, const int* in_sizes, int n_in,
                              void* d_out, int out_size, void* d_ws, size_t ws_size,
                              hipStream_t stream) {
    const float* in   = (const float*)d_in[0];
    const float* W1ih = (const float*)d_in[1];
    const float* W1hh = (const float*)d_in[2];
    const float* W1wh = (const float*)d_in[3];
    const float* b1   = (const float*)d_in[4];
    const float* W2ih = (const float*)d_in[5];
    const float* W2hh = (const float*)d_in[6];
    const float* W2wh = (const float*)d_in[7];
    const float* b2   = (const float*)d_in[8];
    const float* fcw  = (const float*)d_in[9];
    const float* fcb  = (const float*)d_in[10];
    float* out = (float*)d_out;

    // 2 lanes/seq -> 65536 threads -> 1024 waves -> 1 wave/SIMD everywhere
    pewlstm_kernel<<<(BB * 2) / 64, 64, 0, stream>>>(
        in, W1ih, W1hh, W1wh, b1, W2ih, W2hh, W2wh, b2, fcw, fcb, out);
}

// Round 9
// 47.419 us; speedup vs baseline: 1.0548x; 1.0548x over previous
//
#include <hip/hip_runtime.h>

// PewLSTM HS=1, 2-lane systolic (even lane = layer1 @ t, odd = layer2 @ t-1,
// h handed off via DPP quad_perm). R9 = R3 structure + serial-transcendental
// softening: the spine's 2 rcp and the tanh-c exp2 are replaced by short-chain
// software versions (~25/40 cy vs ~100 hw dependent latency); the 4 GATE exp2
// stay hardware (mutually parallel -> only one latency on the spine).
// Spine: gate-fma -> exp2_hw -> rational-combine -> rcp_soft -> exp2_soft
//        -> rcp_soft  (~240 cy vs R3's ~464).

constexpr int BB  = 32768;
constexpr int TT  = 168;
constexpr int CHS = 8;            // timesteps per chunk
constexpr int CHV = 10;           // float4 per chunk
constexpr int NCH = 21;           // chunks

#define LOG2E  1.44269504088896341f
#define NEG2L  (-2.88539008177792681f)
#define ACLAMP 40.0f              // gate-arg clamp: e <= 2^40, den <= 2^120

__device__ __forceinline__ float lane_swap(float x) {   // quad_perm(1,0,3,2)
    return __int_as_float(
        __builtin_amdgcn_mov_dpp(__float_as_int(x), 0xB1, 0xF, 0xF, true));
}

// software rcp, 2x Newton from magic seed: ~5 short levels (~25 cy chain)
// vs ~100 cy hw v_rcp dependent latency. rel err ~1e-6. valid to ~2^120.
__device__ __forceinline__ float rcp2(float x) {
    float y = __int_as_float(0x7EF311C3 - __float_as_int(x));
    float e;
    e = fmaf(-x, y, 1.0f); y = fmaf(y, e, y);
    e = fmaf(-x, y, 1.0f); y = fmaf(y, e, y);
    return y;
}

// software exp2 for x in [-43, 43]: floor/frac + deg-6 poly (Estrin).
// ~8 short levels (~40 cy chain) vs ~100 cy hw v_exp. rel err ~1e-7.
__device__ __forceinline__ float exp2s(float x) {
    float n  = floorf(x);
    float f  = x - n;
    float scale = __int_as_float(((int)n + 127) << 23);
    float f2  = f * f;
    float p01 = fmaf(f, 0.6931471805599453f,    1.0f);
    float p23 = fmaf(f, 0.05550410866482158f,   0.2402265069591007f);
    float p45 = fmaf(f, 0.0013333558146428443f, 0.009618129107628477f);
    float inn = fmaf(f2, 0.00015403530393381606f, p45);
    float f4  = f2 * f2;
    float t1  = fmaf(f2, p23, p01);
    float t2  = fmaf(f4, inn, t1);
    return t2 * scale;
}

__global__ __launch_bounds__(64, 1) void pewlstm_kernel(
    const float* __restrict__ in,
    const float* __restrict__ W1ih, const float* __restrict__ W1hh,
    const float* __restrict__ W1wh, const float* __restrict__ b1,
    const float* __restrict__ W2ih, const float* __restrict__ W2hh,
    const float* __restrict__ W2wh, const float* __restrict__ b2,
    const float* __restrict__ fcw, const float* __restrict__ fcb,
    float* __restrict__ out)
{
    const int tid = blockIdx.x * 64 + threadIdx.x;
    const int b   = tid >> 1;            // sequence index
    const int l2  = tid & 1;             // 1 = layer-2 lane
    const float l2f = l2 ? 1.0f : 0.0f;

    const float* Wih = l2 ? W2ih : W1ih;
    const float* Whh = l2 ? W2hh : W1hh;
    const float* Wwh = l2 ? W2wh : W1wh;
    const float* Bv  = l2 ? b2   : b1;

    // gate order [i,f,g,o]; pre-scale by -log2e (g gate: -2log2e) so the hw
    // exp2 of the scaled pre-activation is e^{-a} (resp. e^{-2a_g}).
    float wih[4], whh[4], bbv[4], wwh[16];
#pragma unroll
    for (int g = 0; g < 4; ++g) {
        const float s = (g == 2) ? NEG2L : -LOG2E;
        wih[g] = Wih[g] * s; whh[g] = Whh[g] * s; bbv[g] = Bv[g] * s;
    }
#pragma unroll
    for (int k = 0; k < 16; ++k) {
        const float s = ((k & 3) == 2) ? NEG2L : -LOG2E;
        wwh[k] = Wwh[k] * s;
    }
    const float fw = fcw[0], fbv = fcb[0];

    const float4* __restrict__ row =
        reinterpret_cast<const float4*>(in + (size_t)b * (TT * 5));
    float4* orow = reinterpret_cast<float4*>(out + (size_t)b * TT);

    float4 pref[CHV];
#pragma unroll
    for (int i = 0; i < CHV; ++i) pref[i] = row[i];

    float h = 0.f, cc = 0.f, h1x = 0.f;
    float xc0 = 0.f, xc1 = 0.f, xc2 = 0.f, xc3 = 0.f;  // prev chunk last weather
    float ob[CHS];
    float pre[CHS][4];
    float cur[CHS * 5];

    auto commit = [&]() {
#pragma unroll
        for (int i = 0; i < CHV; ++i) {
            float4 v = pref[i];
            cur[4*i+0] = v.x; cur[4*i+1] = v.y;
            cur[4*i+2] = v.z; cur[4*i+3] = v.w;
        }
    };
    auto issue = [&](int c2) {
        const float4* nr = row + c2 * CHV;
#pragma unroll
        for (int i = 0; i < CHV; ++i) pref[i] = nr[i];
    };
    auto build = [&]() {   // x-dependent pre-activations (off-spine)
#pragma unroll
        for (int s = 0; s < CHS; ++s) {
            const float w0 = l2 ? (s == 0 ? xc0 : cur[(s-1)*5+0]) : cur[s*5+0];
            const float w1 = l2 ? (s == 0 ? xc1 : cur[(s-1)*5+1]) : cur[s*5+1];
            const float w2 = l2 ? (s == 0 ? xc2 : cur[(s-1)*5+2]) : cur[s*5+2];
            const float w3 = l2 ? (s == 0 ? xc3 : cur[(s-1)*5+3]) : cur[s*5+3];
            const float xi = l2 ? 0.0f : cur[s*5+4];
#pragma unroll
            for (int g = 0; g < 4; ++g) {
                float p = bbv[g];
                p = fmaf(w0, wwh[0  + g], p);
                p = fmaf(w1, wwh[4  + g], p);
                p = fmaf(w2, wwh[8  + g], p);
                p = fmaf(w3, wwh[12 + g], p);
                pre[s][g] = fmaf(xi, wih[g], p);
            }
        }
        xc0 = cur[35]; xc1 = cur[36]; xc2 = cur[37]; xc3 = cur[38];
    };

    auto phase2 = [&](int c, bool is0) {
#pragma unroll
        for (int s = 0; s < CHS; ++s) {
            const float inv = h1x * l2f;           // L2: h1(t-1); L1: 0
            float a0 = fmaf(h, whh[0], fmaf(inv, wih[0], pre[s][0]));
            float a1 = fmaf(h, whh[1], fmaf(inv, wih[1], pre[s][1]));
            float a2 = fmaf(h, whh[2], fmaf(inv, wih[2], pre[s][2]));
            float a3 = fmaf(h, whh[3], fmaf(inv, wih[3], pre[s][3]));
            a0 = fminf(a0, ACLAMP); a1 = fminf(a1, ACLAMP);
            a2 = fminf(a2, ACLAMP); a3 = fminf(a3, ACLAMP);
            const float eI = __builtin_amdgcn_exp2f(a0);   // e^{-a_i}
            const float eF = __builtin_amdgcn_exp2f(a1);   // e^{-a_f}
            const float eG = __builtin_amdgcn_exp2f(a2);   // e^{-2a_g}
            const float eO = __builtin_amdgcn_exp2f(a3);   // e^{-a_o}
            const float dI = 1.f + eI, dF = 1.f + eF;
            const float dG = 1.f + eG, dO = 1.f + eO;
            const float nG = 1.f - eG;
            // c' = (c*dI*dG + nG*dF) / (dF*dI*dG)
            const float p   = dI * dG;
            const float num = fmaf(cc, p, nG * dF);
            cc = num * rcp2(dF * p);
            // h = (1-eC)/(dO*(1+eC)), eC = 2^{clamp(c'*-2log2e)}
            float Cm = cc * NEG2L;
            Cm = fminf(fmaxf(Cm, -43.0f), 43.0f);
            const float eC = exp2s(Cm);
            h = (1.f - eC) * rcp2(dO * (1.f + eC));

            if (s == 0 && is0) { if (l2) { h = 0.f; cc = 0.f; } }  // phantom

            ob[(s + 7) & 7] = fmaf(h, fw, fbv);    // true h2 on l2 lane

            if (s == 0 && c >= 1 && l2) {          // flush prev chunk outputs
                orow[(c-1)*2+0] = make_float4(ob[0], ob[1], ob[2], ob[3]);
                orow[(c-1)*2+1] = make_float4(ob[4], ob[5], ob[6], ob[7]);
            }

            h1x = lane_swap(h);                    // partner's h
        }
    };

    // ---- prologue: chunk 0 ----
    commit();
    build();
    issue(1);

    // ---- main loop ----
    for (int c = 0; c < NCH - 1; ++c) {
        phase2(c, c == 0);        // consume chunk c's pre
        commit();                 // cur = chunk c+1
        if (c + 2 < NCH) issue(c + 2);
        build();                  // pre for chunk c+1
    }
    phase2(NCH - 1, false);

    // ---- epilogue iteration t=168: L2 computes h2(167) ----
    {
        float a[4];
#pragma unroll
        for (int g = 0; g < 4; ++g) {
            float pp = bbv[g];
            pp = fmaf(xc0, wwh[0  + g], pp);
            pp = fmaf(xc1, wwh[4  + g], pp);
            pp = fmaf(xc2, wwh[8  + g], pp);
            pp = fmaf(xc3, wwh[12 + g], pp);
            pp = fmaf(h1x, wih[g], pp);
            a[g] = fminf(fmaf(h, whh[g], pp), ACLAMP);
        }
        const float eI = __builtin_amdgcn_exp2f(a[0]);
        const float eF = __builtin_amdgcn_exp2f(a[1]);
        const float eG = __builtin_amdgcn_exp2f(a[2]);
        const float eO = __builtin_amdgcn_exp2f(a[3]);
        const float dI = 1.f + eI, dF = 1.f + eF;
        const float dG = 1.f + eG, dO = 1.f + eO;
        const float nG = 1.f - eG;
        const float p   = dI * dG;
        const float num = fmaf(cc, p, nG * dF);
        cc = num * rcp2(dF * p);
        float Cm = cc * NEG2L;
        Cm = fminf(fmaxf(Cm, -43.0f), 43.0f);
        const float eC = exp2s(Cm);
        h = (1.f - eC) * rcp2(dO * (1.f + eC));
        ob[7] = fmaf(h, fw, fbv);
        if (l2) {
            orow[(NCH-1)*2+0] = make_float4(ob[0], ob[1], ob[2], ob[3]);
            orow[(NCH-1)*2+1] = make_float4(ob[4], ob[5], ob[6], ob[7]);
        }
    }
}

extern "C" void kernel_launch(void* const* d_in, const int* in_sizes, int n_in,
                              void* d_out, int out_size, void* d_ws, size_t ws_size,
                              hipStream_t stream) {
    const float* in   = (const float*)d_in[0];
    const float* W1ih = (const float*)d_in[1];
    const float* W1hh = (const float*)d_in[2];
    const float* W1wh = (const float*)d_in[3];
    const float* b1   = (const float*)d_in[4];
    const float* W2ih = (const float*)d_in[5];
    const float* W2hh = (const float*)d_in[6];
    const float* W2wh = (const float*)d_in[7];
    const float* b2   = (const float*)d_in[8];
    const float* fcw  = (const float*)d_in[9];
    const float* fcb  = (const float*)d_in[10];
    float* out = (float*)d_out;

    // 2 lanes/seq -> 65536 threads -> 1024 waves -> 1 wave/SIMD everywhere
    pewlstm_kernel<<<(BB * 2) / 64, 64, 0, stream>>>(
        in, W1ih, W1hh, W1wh, b1, W2ih, W2hh, W2wh, b2, fcw, fcb, out);
}

// Round 10
// 43.629 us; speedup vs baseline: 1.1464x; 1.0869x over previous
//
#include <hip/hip_runtime.h>

// PewLSTM HS=1, 2-lane systolic (even lane = layer1 @ t, odd = layer2 @ t-1,
// h via DPP quad_perm). R10 = R9's mixed hw/soft spine WITHOUT the pre[]
// staging buffer that spilled in R9 (WRITE_SIZE 27->52MB). Gate pre-acts are
// computed inline per step (off-chain anyway); the 4 gate exp2 stay HW
// (mutually parallel -> one latency level); the SERIAL tail (rcp, tanh-c
// exp2, rcp) is software with ~20-26 cy chains vs ~100 cy hw dep latency.

constexpr int BB  = 32768;
constexpr int TT  = 168;
constexpr int CHS = 8;            // timesteps per chunk
constexpr int CHV = 10;           // float4 per chunk
constexpr int NCH = 21;           // chunks

#define LOG2E  1.44269504088896341f
#define NEG2L  (-2.88539008177792681f)
#define PCL    36.0f              // off-spine pre-act clamp: den <= 2^117

__device__ __forceinline__ float lane_swap(float x) {   // quad_perm(1,0,3,2)
    return __int_as_float(
        __builtin_amdgcn_mov_dpp(__float_as_int(x), 0xB1, 0xF, 0xF, true));
}

// software rcp: magic seed + 2 NR. chain ~20 cy vs ~100 hw. valid to ~2^120.
__device__ __forceinline__ float rcp2(float x) {
    float y = __int_as_float(0x7EF311C3 - __float_as_int(x));
    float e;
    e = fmaf(-x, y, 1.0f); y = fmaf(y, e, y);
    e = fmaf(-x, y, 1.0f); y = fmaf(y, e, y);
    return y;
}

// software exp2, x in [-126, 43]: floor/frac + deg-6 Estrin. chain ~26 cy.
__device__ __forceinline__ float exp2s(float x) {
    float n  = floorf(x);
    float f  = x - n;
    float scale = __int_as_float(((int)n + 127) << 23);
    float f2  = f * f;
    float p01 = fmaf(f, 0.6931471805599453f,    1.0f);
    float p23 = fmaf(f, 0.05550410866482158f,   0.2402265069591007f);
    float p45 = fmaf(f, 0.0013333558146428443f, 0.009618129107628477f);
    float inn = fmaf(f2, 0.00015403530393381606f, p45);
    float f4  = f2 * f2;
    float t1  = fmaf(f2, p23, p01);
    float t2  = fmaf(f4, inn, t1);
    return t2 * scale;
}

__global__ __launch_bounds__(64, 1) void pewlstm_kernel(
    const float* __restrict__ in,
    const float* __restrict__ W1ih, const float* __restrict__ W1hh,
    const float* __restrict__ W1wh, const float* __restrict__ b1,
    const float* __restrict__ W2ih, const float* __restrict__ W2hh,
    const float* __restrict__ W2wh, const float* __restrict__ b2,
    const float* __restrict__ fcw, const float* __restrict__ fcb,
    float* __restrict__ out)
{
    const int tid = blockIdx.x * 64 + threadIdx.x;
    const int b   = tid >> 1;            // sequence index
    const int l2  = tid & 1;             // 1 = layer-2 lane
    const float l2f = l2 ? 1.0f : 0.0f;

    const float* Wih = l2 ? W2ih : W1ih;
    const float* Whh = l2 ? W2hh : W1hh;
    const float* Wwh = l2 ? W2wh : W1wh;
    const float* Bv  = l2 ? b2   : b1;

    // gate order [i,f,g,o]; pre-scale by -log2e (g gate: -2log2e):
    // hw exp2 of scaled pre-activation = e^{-a} (resp. e^{-2a_g}).
    float wih[4], whh[4], bbv[4], wwh[16];
#pragma unroll
    for (int g = 0; g < 4; ++g) {
        const float s = (g == 2) ? NEG2L : -LOG2E;
        wih[g] = Wih[g] * s; whh[g] = Whh[g] * s; bbv[g] = Bv[g] * s;
    }
#pragma unroll
    for (int k = 0; k < 16; ++k) {
        const float s = ((k & 3) == 2) ? NEG2L : -LOG2E;
        wwh[k] = Wwh[k] * s;
    }
    const float fw = fcw[0], fbv = fcb[0];

    const float4* __restrict__ row =
        reinterpret_cast<const float4*>(in + (size_t)b * (TT * 5));
    float4* orow = reinterpret_cast<float4*>(out + (size_t)b * TT);

    float4 pref[CHV];
#pragma unroll
    for (int i = 0; i < CHV; ++i) pref[i] = row[i];

    float cur[CHS * 5];
    float h = 0.f, cc = 0.f, h1x = 0.f;
    float xc0 = 0.f, xc1 = 0.f, xc2 = 0.f, xc3 = 0.f;  // prev chunk last weather
    float ob[CHS];

    auto commit = [&]() {
#pragma unroll
        for (int i = 0; i < CHV; ++i) {
            float4 v = pref[i];
            cur[4*i+0] = v.x; cur[4*i+1] = v.y;
            cur[4*i+2] = v.z; cur[4*i+3] = v.w;
        }
    };
    auto issue = [&](int c2) {
        const float4* nr = row + c2 * CHV;
#pragma unroll
        for (int i = 0; i < CHV; ++i) pref[i] = nr[i];
    };

    commit();            // cur = chunk 0
    issue(1);            // pref <- chunk 1 (in flight during processing)

    for (int c = 0; c < NCH; ++c) {
#pragma unroll
        for (int s = 0; s < CHS; ++s) {
            // my step's inputs: L1 -> step t; L2 -> step t-1
            const float w0 = l2 ? (s == 0 ? xc0 : cur[(s-1)*5+0]) : cur[s*5+0];
            const float w1 = l2 ? (s == 0 ? xc1 : cur[(s-1)*5+1]) : cur[s*5+1];
            const float w2 = l2 ? (s == 0 ? xc2 : cur[(s-1)*5+2]) : cur[s*5+2];
            const float w3 = l2 ? (s == 0 ? xc3 : cur[(s-1)*5+3]) : cur[s*5+3];
            const float xi = l2 ? 0.0f : cur[s*5+4];

            // off-spine: x-dependent pre-activations, clamped here (not on chain)
            float p0 = bbv[0], p1 = bbv[1], p2 = bbv[2], p3 = bbv[3];
            p0 = fmaf(w0, wwh[0],  p0); p1 = fmaf(w0, wwh[1],  p1);
            p2 = fmaf(w0, wwh[2],  p2); p3 = fmaf(w0, wwh[3],  p3);
            p0 = fmaf(w1, wwh[4],  p0); p1 = fmaf(w1, wwh[5],  p1);
            p2 = fmaf(w1, wwh[6],  p2); p3 = fmaf(w1, wwh[7],  p3);
            p0 = fmaf(w2, wwh[8],  p0); p1 = fmaf(w2, wwh[9],  p1);
            p2 = fmaf(w2, wwh[10], p2); p3 = fmaf(w2, wwh[11], p3);
            p0 = fmaf(w3, wwh[12], p0); p1 = fmaf(w3, wwh[13], p1);
            p2 = fmaf(w3, wwh[14], p2); p3 = fmaf(w3, wwh[15], p3);
            p0 = fmaf(xi, wih[0], p0);  p1 = fmaf(xi, wih[1], p1);
            p2 = fmaf(xi, wih[2], p2);  p3 = fmaf(xi, wih[3], p3);
            p0 = fminf(p0, PCL); p1 = fminf(p1, PCL);
            p2 = fminf(p2, PCL); p3 = fminf(p3, PCL);

            // spine: 2 fma -> hw exp2 (x4 parallel) -> rational -> soft tail
            const float inv = h1x * l2f;            // L2: h1(t-1); L1: 0
            const float a0 = fmaf(h, whh[0], fmaf(inv, wih[0], p0));
            const float a1 = fmaf(h, whh[1], fmaf(inv, wih[1], p1));
            const float a2 = fmaf(h, whh[2], fmaf(inv, wih[2], p2));
            const float a3 = fmaf(h, whh[3], fmaf(inv, wih[3], p3));
            const float eI = __builtin_amdgcn_exp2f(a0);   // e^{-a_i}
            const float eF = __builtin_amdgcn_exp2f(a1);   // e^{-a_f}
            const float eG = __builtin_amdgcn_exp2f(a2);   // e^{-2a_g}
            const float eO = __builtin_amdgcn_exp2f(a3);   // e^{-a_o}
            const float dI = 1.f + eI, dF = 1.f + eF;
            const float dG = 1.f + eG, dO = 1.f + eO;
            const float nG = 1.f - eG;
            // c' = (c*dI*dG + nG*dF) / (dF*dI*dG)
            const float p   = dI * dG;
            const float den = dF * p;
            const float num = fmaf(cc, p, nG * dF);
            cc = num * rcp2(den);
            // h = (1-eC)/(dO*(1+eC)), eC = 2^{med3(c'*-2log2e)}
            float Cm = cc * NEG2L;
            Cm = fminf(fmaxf(Cm, -126.0f), 43.0f);  // single v_med3
            const float eC = exp2s(Cm);
            h = (1.f - eC) * rcp2(dO * (1.f + eC));

            if (s == 0 && c == 0) { if (l2) { h = 0.f; cc = 0.f; } }  // phantom

            ob[(s + 7) & 7] = fmaf(h, fw, fbv);     // true h2 on l2 lane

            if (s == 0 && c >= 1 && l2) {           // flush prev chunk outputs
                orow[(c-1)*2+0] = make_float4(ob[0], ob[1], ob[2], ob[3]);
                orow[(c-1)*2+1] = make_float4(ob[4], ob[5], ob[6], ob[7]);
            }

            h1x = lane_swap(h);                     // partner's h
        }
        // capture last weather of this chunk BEFORE overwriting cur
        xc0 = cur[35]; xc1 = cur[36]; xc2 = cur[37]; xc3 = cur[38];
        if (c < NCH - 1) {
            commit();                               // cur = chunk c+1
            if (c + 2 < NCH) issue(c + 2);
        }
    }

    // epilogue iteration t=168: L2 lane computes h2(167)
    {
        float a[4];
#pragma unroll
        for (int g = 0; g < 4; ++g) {
            float pp = bbv[g];
            pp = fmaf(xc0, wwh[0  + g], pp);
            pp = fmaf(xc1, wwh[4  + g], pp);
            pp = fmaf(xc2, wwh[8  + g], pp);
            pp = fmaf(xc3, wwh[12 + g], pp);
            pp = fminf(pp, PCL);
            pp = fmaf(h1x, wih[g], pp);
            a[g] = fmaf(h, whh[g], pp);
        }
        const float eI = __builtin_amdgcn_exp2f(a[0]);
        const float eF = __builtin_amdgcn_exp2f(a[1]);
        const float eG = __builtin_amdgcn_exp2f(a[2]);
        const float eO = __builtin_amdgcn_exp2f(a[3]);
        const float dI = 1.f + eI, dF = 1.f + eF;
        const float dG = 1.f + eG, dO = 1.f + eO;
        const float nG = 1.f - eG;
        const float p   = dI * dG;
        const float num = fmaf(cc, p, nG * dF);
        cc = num * rcp2(dF * p);
        float Cm = cc * NEG2L;
        Cm = fminf(fmaxf(Cm, -126.0f), 43.0f);
        const float eC = exp2s(Cm);
        h = (1.f - eC) * rcp2(dO * (1.f + eC));
        ob[7] = fmaf(h, fw, fbv);
        if (l2) {
            orow[(NCH-1)*2+0] = make_float4(ob[0], ob[1], ob[2], ob[3]);
            orow[(NCH-1)*2+1] = make_float4(ob[4], ob[5], ob[6], ob[7]);
        }
    }
}

extern "C" void kernel_launch(void* const* d_in, const int* in_sizes, int n_in,
                              void* d_out, int out_size, void* d_ws, size_t ws_size,
                              hipStream_t stream) {
    const float* in   = (const float*)d_in[0];
    const float* W1ih = (const float*)d_in[1];
    const float* W1hh = (const float*)d_in[2];
    const float* W1wh = (const float*)d_in[3];
    const float* b1   = (const float*)d_in[4];
    const float* W2ih = (const float*)d_in[5];
    const float* W2hh = (const float*)d_in[6];
    const float* W2wh = (const float*)d_in[7];
    const float* b2   = (const float*)d_in[8];
    const float* fcw  = (const float*)d_in[9];
    const float* fcb  = (const float*)d_in[10];
    float* out = (float*)d_out;

    // 2 lanes/seq -> 65536 threads -> 1024 waves -> 1 wave/SIMD everywhere
    pewlstm_kernel<<<(BB * 2) / 64, 64, 0, stream>>>(
        in, W1ih, W1hh, W1wh, b1, W2ih, W2hh, W2wh, b2, fcw, fcb, out);
}